// Round 6
// baseline (902.382 us; speedup 1.0000x reference)
//
#include <hip/hip_runtime.h>

#define NBATCH 256
#define P 1024
#define Q 128
#define NS_LOOP 10

typedef _Float16 half8 __attribute__((ext_vector_type(8)));
typedef float f32x4 __attribute__((ext_vector_type(4)));
struct Half4 { _Float16 x, y, z, w; };   // 8 bytes

// Swizzled fp16 storage for 128x128 symmetric matrices:
// element (r,c) -> Half4 slot r*32 + ((c>>2) ^ (r&15)), component c&3.
__device__ __forceinline__ half8 frag_ld(const Half4* S, int rowbase, int slotbase, int lane) {
    const int r = rowbase + (lane & 15);
    const int g = (lane >> 4);
    const int rx = r & 15;
    const Half4 h1 = S[r * 32 + ((slotbase + g) ^ rx)];
    const Half4 h2 = S[r * 32 + ((slotbase + g + 4) ^ rx)];
    half8 v;
    v[0] = h1.x; v[1] = h1.y; v[2] = h1.z; v[3] = h1.w;
    v[4] = h2.x; v[5] = h2.y; v[6] = h2.z; v[7] = h2.w;
    return v;
}

// C-fragment position, stored TRANSPOSED (ok: all iterates symmetric to O(eps)).
__device__ __forceinline__ int cpos(int RB, int CB, int lane) {
    const int r = CB + (lane & 15);
    const int s = (RB >> 2) + (lane >> 4);
    return r * 32 + (s ^ (r & 15));
}

__device__ __forceinline__ f32x4 cread(const Half4* S, int p) {
    const Half4 h = S[p];
    f32x4 v;
    v[0] = (float)h.x; v[1] = (float)h.y; v[2] = (float)h.z; v[3] = (float)h.w;
    return v;
}

__device__ __forceinline__ void cwrite(Half4* S, int p, f32x4 v) {
    Half4 h;
    h.x = (_Float16)v[0]; h.y = (_Float16)v[1]; h.z = (_Float16)v[2]; h.w = (_Float16)v[3];
    S[p] = h;
}

// ---------------------------------------------------------------------------
// Kernel 1: gram[n] = temp^T temp (fp32 VALU). Standalone for clean counters.
// ---------------------------------------------------------------------------
__global__ __launch_bounds__(512) void gram_kernel(
    const float* __restrict__ X, const float* __restrict__ G,
    const float* __restrict__ lrp, float* __restrict__ gram)
{
    __shared__ float sT[32 * Q];   // 16 KB
    const int n = blockIdx.x;
    const int tid = threadIdx.x;
    const float lr = *lrp;
    const float* xb = X + (size_t)n * P * Q;
    const float* gb = G + (size_t)n * P * Q;
    const int ty = tid >> 5, tx = tid & 31;

    float acc[8][4];
#pragma unroll
    for (int i = 0; i < 8; ++i)
#pragma unroll
        for (int j = 0; j < 4; ++j) acc[i][j] = 0.0f;

    float4 tA[2], tB[2];
#pragma unroll
    for (int t = 0; t < 2; ++t) {
        const int idx = tid + t * 512;
        const float4 xv = ((const float4*)xb)[idx];
        const float4 gv = ((const float4*)gb)[idx];
        tA[t] = make_float4(xv.x - lr * gv.x, xv.y - lr * gv.y,
                            xv.z - lr * gv.z, xv.w - lr * gv.w);
    }

    for (int c = 0; c < 32; c += 2) {
        __syncthreads();
#pragma unroll
        for (int t = 0; t < 2; ++t) ((float4*)sT)[tid + t * 512] = tA[t];
        {
            const float4* xc = (const float4*)(xb + (size_t)(c + 1) * 32 * Q);
            const float4* gc = (const float4*)(gb + (size_t)(c + 1) * 32 * Q);
#pragma unroll
            for (int t = 0; t < 2; ++t) {
                const int idx = tid + t * 512;
                const float4 xv = xc[idx];
                const float4 gv = gc[idx];
                tB[t] = make_float4(xv.x - lr * gv.x, xv.y - lr * gv.y,
                                    xv.z - lr * gv.z, xv.w - lr * gv.w);
            }
        }
        __syncthreads();
        for (int p = 0; p < 32; ++p) {
            float a[8];
#pragma unroll
            for (int i = 0; i < 8; ++i) a[i] = sT[p * 128 + ty * 8 + i];
            const float4 bv = ((const float4*)(sT + p * 128))[tx];
            const float b[4] = {bv.x, bv.y, bv.z, bv.w};
#pragma unroll
            for (int i = 0; i < 8; ++i)
#pragma unroll
                for (int j = 0; j < 4; ++j) acc[i][j] += a[i] * b[j];
        }
        __syncthreads();
#pragma unroll
        for (int t = 0; t < 2; ++t) ((float4*)sT)[tid + t * 512] = tB[t];
        if (c + 2 < 32) {
            const float4* xc = (const float4*)(xb + (size_t)(c + 2) * 32 * Q);
            const float4* gc = (const float4*)(gb + (size_t)(c + 2) * 32 * Q);
#pragma unroll
            for (int t = 0; t < 2; ++t) {
                const int idx = tid + t * 512;
                const float4 xv = xc[idx];
                const float4 gv = gc[idx];
                tA[t] = make_float4(xv.x - lr * gv.x, xv.y - lr * gv.y,
                                    xv.z - lr * gv.z, xv.w - lr * gv.w);
            }
        }
        __syncthreads();
        for (int p = 0; p < 32; ++p) {
            float a[8];
#pragma unroll
            for (int i = 0; i < 8; ++i) a[i] = sT[p * 128 + ty * 8 + i];
            const float4 bv = ((const float4*)(sT + p * 128))[tx];
            const float b[4] = {bv.x, bv.y, bv.z, bv.w};
#pragma unroll
            for (int i = 0; i < 8; ++i)
#pragma unroll
                for (int j = 0; j < 4; ++j) acc[i][j] += a[i] * b[j];
        }
    }

    float* gmo = gram + (size_t)n * Q * Q;
#pragma unroll
    for (int i = 0; i < 8; ++i) {
        float4 v = make_float4(acc[i][0], acc[i][1], acc[i][2], acc[i][3]);
        ((float4*)(gmo + (size_t)(ty * 8 + i) * Q))[tx] = v;
    }
}

// ---------------------------------------------------------------------------
// Kernel 2: Newton-Schulz (fp16 MFMA), register-lean. 512 thr = 8 waves,
// each wave owns a 16-row strip: a[8] f32x4 accumulators (32 VGPR), peak
// live ~80 regs -> no spill possible at cap 128.
// W-update ping-pongs cur<->scr (M's buffer becomes Wnew's buffer).
//   M = 1.5W - 0.5 W*W      (-> scr)
//   Wnew = 1.5M - 0.5 M*W   (regs, then -> scr after barrier)
//   Znew = 1.5Z - 0.5 Wnew*Z
// LDS: 2 W-buffers + Z, fp16 swizzled, 32KB each = 96KB.
// ---------------------------------------------------------------------------
__global__ __launch_bounds__(512) void ns_kernel(
    const float* __restrict__ gram, float* __restrict__ Zg)
{
    __shared__ __align__(16) unsigned char pool[98304];
    Half4* bufA = (Half4*)pool;
    Half4* bufB = (Half4*)(pool + 32768);
    Half4* sZh  = (Half4*)(pool + 65536);
    __shared__ float sRed[8];

    const int n = blockIdx.x;
    const int tid = threadIdx.x;
    const float* gm = gram + (size_t)n * Q * Q;

    // ---- load gram, Frobenius norm ----
    float4 gv[8];
    float ss = 0.0f;
#pragma unroll
    for (int t = 0; t < 8; ++t) {
        gv[t] = ((const float4*)gm)[tid + t * 512];
        ss += gv[t].x * gv[t].x + gv[t].y * gv[t].y
            + gv[t].z * gv[t].z + gv[t].w * gv[t].w;
    }
#pragma unroll
    for (int off = 32; off > 0; off >>= 1) ss += __shfl_down(ss, off, 64);
    if ((tid & 63) == 0) sRed[tid >> 6] = ss;
    __syncthreads();
    float csum = 0.0f;
#pragma unroll
    for (int w = 0; w < 8; ++w) csum += sRed[w];
    const float c = sqrtf(csum);
    const float rc = 1.0f / c;
    const float rs = 1.0f / sqrtf(c);

    // ---- init W0 = gram/c, Z0 = 1.5I - 0.5 W0 (fp16 swizzled) ----
#pragma unroll
    for (int t = 0; t < 8; ++t) {
        const int idx = tid + t * 512;       // Half4-slot linear index
        const int row = idx >> 5, c4 = idx & 31;
        const int slot = row * 32 + (c4 ^ (row & 15));
        float wv[4], zv[4];
        wv[0] = gv[t].x * rc; wv[1] = gv[t].y * rc;
        wv[2] = gv[t].z * rc; wv[3] = gv[t].w * rc;
#pragma unroll
        for (int j = 0; j < 4; ++j)
            zv[j] = -0.5f * wv[j] + (((row >> 2) == c4 && (row & 3) == j) ? 1.5f : 0.0f);
        Half4 wh, zh;
        wh.x = (_Float16)wv[0]; wh.y = (_Float16)wv[1]; wh.z = (_Float16)wv[2]; wh.w = (_Float16)wv[3];
        zh.x = (_Float16)zv[0]; zh.y = (_Float16)zv[1]; zh.z = (_Float16)zv[2]; zh.w = (_Float16)zv[3];
        bufA[slot] = wh;
        sZh[slot] = zh;
    }
    __syncthreads();

    const int lane = tid & 63;
    const int wid = tid >> 6;       // 8 waves
    const int RB = wid * 16;        // own 16-row strip
    const f32x4 zero4 = {0.0f, 0.0f, 0.0f, 0.0f};
    Half4* cur = bufA;
    Half4* scr = bufB;

    for (int it = 0; it < NS_LOOP; ++it) {
        // --- GEMM1: M = 1.5W - 0.5 W*W -> scr ---
        f32x4 a1[8];
#pragma unroll
        for (int fj = 0; fj < 8; ++fj) a1[fj] = zero4;
#pragma unroll
        for (int kb = 0; kb < 4; ++kb) {
            const half8 af = frag_ld(cur, RB, kb * 8, lane);
#pragma unroll
            for (int fj = 0; fj < 8; ++fj) {
                const half8 bf = frag_ld(cur, fj * 16, kb * 8, lane);
                a1[fj] = __builtin_amdgcn_mfma_f32_16x16x32_f16(af, bf, a1[fj], 0, 0, 0);
            }
        }
#pragma unroll
        for (int fj = 0; fj < 8; ++fj) {
            const int p = cpos(RB, fj * 16, lane);
            cwrite(scr, p, 1.5f * cread(cur, p) - 0.5f * a1[fj]);
        }
        __syncthreads();   // M visible

        // --- GEMM2: Wnew = 1.5M - 0.5 M*W (regs) ---
        f32x4 a2[8];
#pragma unroll
        for (int fj = 0; fj < 8; ++fj) a2[fj] = zero4;
#pragma unroll
        for (int kb = 0; kb < 4; ++kb) {
            const half8 af = frag_ld(scr, RB, kb * 8, lane);
#pragma unroll
            for (int fj = 0; fj < 8; ++fj) {
                const half8 bf = frag_ld(cur, fj * 16, kb * 8, lane);
                a2[fj] = __builtin_amdgcn_mfma_f32_16x16x32_f16(af, bf, a2[fj], 0, 0, 0);
            }
        }
        f32x4 wn[8];
#pragma unroll
        for (int fj = 0; fj < 8; ++fj) {
            const int p = cpos(RB, fj * 16, lane);
            wn[fj] = 1.5f * cread(scr, p) - 0.5f * a2[fj];
        }
        __syncthreads();   // all M reads done
#pragma unroll
        for (int fj = 0; fj < 8; ++fj)
            cwrite(scr, cpos(RB, fj * 16, lane), wn[fj]);
        __syncthreads();   // Wnew visible (in scr)

        // --- GEMM3: Znew = 1.5Z - 0.5 Wnew*Z ---
        f32x4 a3[8];
#pragma unroll
        for (int fj = 0; fj < 8; ++fj) a3[fj] = zero4;
#pragma unroll
        for (int kb = 0; kb < 4; ++kb) {
            const half8 af = frag_ld(scr, RB, kb * 8, lane);
#pragma unroll
            for (int fj = 0; fj < 8; ++fj) {
                const half8 bf = frag_ld(sZh, fj * 16, kb * 8, lane);
                a3[fj] = __builtin_amdgcn_mfma_f32_16x16x32_f16(af, bf, a3[fj], 0, 0, 0);
            }
        }
        f32x4 zn[8];
#pragma unroll
        for (int fj = 0; fj < 8; ++fj) {
            const int p = cpos(RB, fj * 16, lane);
            zn[fj] = 1.5f * cread(sZh, p) - 0.5f * a3[fj];
        }
        __syncthreads();   // all Z reads done
#pragma unroll
        for (int fj = 0; fj < 8; ++fj)
            cwrite(sZh, cpos(RB, fj * 16, lane), zn[fj]);
        __syncthreads();

        // swap: scr now holds W, cur becomes scratch
        Half4* tmp = cur; cur = scr; scr = tmp;
    }

    // ---- Zg = Z / sqrt(c) ----
    float* zo = Zg + (size_t)n * Q * Q;
#pragma unroll
    for (int t = 0; t < 8; ++t) {
        const int idx = tid + t * 512;
        const int row = idx >> 5, c4 = idx & 31;
        const Half4 h = sZh[row * 32 + (c4 ^ (row & 15))];
        float4 o;
        o.x = (float)h.x * rs; o.y = (float)h.y * rs;
        o.z = (float)h.z * rs; o.w = (float)h.w * rs;
        ((float4*)(zo + row * Q))[c4] = o;
    }
}

// ---------------------------------------------------------------------------
// Kernel 3: one fp32 NS refinement step (quadratic cleanup of fp16 noise).
//   Z = 1.5Y - 0.5 * Y*(S*(Y*Y)), exact operand order (no commuting).
// ---------------------------------------------------------------------------
__global__ __launch_bounds__(512) void refine_kernel(
    const float* __restrict__ gram, float* __restrict__ Zg)
{
    __shared__ float sY[Q * Q];
    __shared__ float sU[Q * Q];
    __shared__ float sR[32 * Q];
    const int n = blockIdx.x;
    const int tid = threadIdx.x;
    const float* gm = gram + (size_t)n * Q * Q;
    float* zg = Zg + (size_t)n * Q * Q;
    const int ty = tid >> 5, tx = tid & 31;

#pragma unroll
    for (int t = 0; t < 8; ++t) {
        const int idx = tid + t * 512;
        ((float4*)sY)[idx] = ((const float4*)zg)[idx];
    }
    __syncthreads();

    // U = Y*Y
    {
        float acc[8][4];
#pragma unroll
        for (int i = 0; i < 8; ++i)
#pragma unroll
            for (int j = 0; j < 4; ++j) acc[i][j] = 0.0f;
        for (int k = 0; k < Q; ++k) {
            float a[8];
#pragma unroll
            for (int i = 0; i < 8; ++i) a[i] = sY[(ty * 8 + i) * Q + k];
            const float4 bv = ((const float4*)(sY + k * Q))[tx];
            const float b[4] = {bv.x, bv.y, bv.z, bv.w};
#pragma unroll
            for (int i = 0; i < 8; ++i)
#pragma unroll
                for (int j = 0; j < 4; ++j) acc[i][j] += a[i] * b[j];
        }
#pragma unroll
        for (int i = 0; i < 8; ++i) {
            float4 v = make_float4(acc[i][0], acc[i][1], acc[i][2], acc[i][3]);
            ((float4*)(sU + (ty * 8 + i) * Q))[tx] = v;
        }
    }
    __syncthreads();

    for (int ch = 0; ch < 4; ++ch) {
        const int r0 = ch * 32 + ty * 2;
        float acc[2][4];
#pragma unroll
        for (int i = 0; i < 2; ++i)
#pragma unroll
            for (int j = 0; j < 4; ++j) acc[i][j] = 0.0f;
        for (int k = 0; k < Q; ++k) {
            const float a0 = sY[(r0 + 0) * Q + k];
            const float a1 = sY[(r0 + 1) * Q + k];
            const float4 bv = ((const float4*)(gm + (size_t)k * Q))[tx];
            acc[0][0] += a0 * bv.x; acc[0][1] += a0 * bv.y;
            acc[0][2] += a0 * bv.z; acc[0][3] += a0 * bv.w;
            acc[1][0] += a1 * bv.x; acc[1][1] += a1 * bv.y;
            acc[1][2] += a1 * bv.z; acc[1][3] += a1 * bv.w;
        }
        __syncthreads();
#pragma unroll
        for (int i = 0; i < 2; ++i) {
            float4 v = make_float4(acc[i][0], acc[i][1], acc[i][2], acc[i][3]);
            ((float4*)(sR + (ty * 2 + i) * Q))[tx] = v;
        }
        __syncthreads();

        float acc2[2][4];
#pragma unroll
        for (int i = 0; i < 2; ++i)
#pragma unroll
            for (int j = 0; j < 4; ++j) acc2[i][j] = 0.0f;
        for (int k = 0; k < Q; ++k) {
            const float a0 = sR[(ty * 2 + 0) * Q + k];
            const float a1 = sR[(ty * 2 + 1) * Q + k];
            const float4 bv = ((const float4*)(sU + k * Q))[tx];
            acc2[0][0] += a0 * bv.x; acc2[0][1] += a0 * bv.y;
            acc2[0][2] += a0 * bv.z; acc2[0][3] += a0 * bv.w;
            acc2[1][0] += a1 * bv.x; acc2[1][1] += a1 * bv.y;
            acc2[1][2] += a1 * bv.z; acc2[1][3] += a1 * bv.w;
        }
#pragma unroll
        for (int i = 0; i < 2; ++i) {
            const float4 yv = ((const float4*)(sY + (r0 + i) * Q))[tx];
            float4 o;
            o.x = 1.5f * yv.x - 0.5f * acc2[i][0];
            o.y = 1.5f * yv.y - 0.5f * acc2[i][1];
            o.z = 1.5f * yv.z - 0.5f * acc2[i][2];
            o.w = 1.5f * yv.w - 0.5f * acc2[i][3];
            ((float4*)(zg + (size_t)(r0 + i) * Q))[tx] = o;
        }
    }
}

// ---------------------------------------------------------------------------
// Kernel 4: out[n] = temp[n] @ Zg[n]. 2 blocks/batch, 512 threads.
// ---------------------------------------------------------------------------
__global__ __launch_bounds__(512) void apply_kernel(
    const float* __restrict__ X, const float* __restrict__ G,
    const float* __restrict__ lrp, const float* __restrict__ Zg,
    float* __restrict__ out)
{
    __shared__ float sZf[Q * Q];
    __shared__ float sT2[128 * Q];

    const int n = blockIdx.x >> 1;
    const int rb = (blockIdx.x & 1) * 512;
    const int tid = threadIdx.x;
    const float lr = *lrp;
    const float* xb = X + (size_t)n * P * Q + (size_t)rb * Q;
    const float* gb = G + (size_t)n * P * Q + (size_t)rb * Q;
    float* ob = out + (size_t)n * P * Q + (size_t)rb * Q;

#pragma unroll
    for (int t = 0; t < 8; ++t) {
        const int idx = tid + t * 512;
        ((float4*)sZf)[idx] = ((const float4*)(Zg + (size_t)n * Q * Q))[idx];
    }

    const int ty = tid >> 5, tx = tid & 31;
    float4 tA[8], tB[8];
#pragma unroll
    for (int t = 0; t < 8; ++t) {
        const int idx = tid + t * 512;
        const float4 xv = ((const float4*)xb)[idx];
        const float4 gv = ((const float4*)gb)[idx];
        tA[t] = make_float4(xv.x - lr * gv.x, xv.y - lr * gv.y,
                            xv.z - lr * gv.z, xv.w - lr * gv.w);
    }

    for (int ch = 0; ch < 4; ch += 2) {
        __syncthreads();
#pragma unroll
        for (int t = 0; t < 8; ++t) ((float4*)sT2)[tid + t * 512] = tA[t];
        {
            const float4* xc = (const float4*)(xb + (size_t)(ch + 1) * 128 * Q);
            const float4* gc = (const float4*)(gb + (size_t)(ch + 1) * 128 * Q);
#pragma unroll
            for (int t = 0; t < 8; ++t) {
                const int idx = tid + t * 512;
                const float4 xv = xc[idx];
                const float4 gv = gc[idx];
                tB[t] = make_float4(xv.x - lr * gv.x, xv.y - lr * gv.y,
                                    xv.z - lr * gv.z, xv.w - lr * gv.w);
            }
        }
        __syncthreads();
        {
            float acc[8][4];
#pragma unroll
            for (int i = 0; i < 8; ++i)
#pragma unroll
                for (int j = 0; j < 4; ++j) acc[i][j] = 0.0f;
            for (int k = 0; k < Q; ++k) {
                float a[8];
#pragma unroll
                for (int i = 0; i < 8; ++i) a[i] = sT2[(ty * 8 + i) * 128 + k];
                const float4 bv = ((const float4*)(sZf + k * Q))[tx];
                const float b[4] = {bv.x, bv.y, bv.z, bv.w};
#pragma unroll
                for (int i = 0; i < 8; ++i)
#pragma unroll
                    for (int j = 0; j < 4; ++j) acc[i][j] += a[i] * b[j];
            }
            float* oc = ob + (size_t)ch * 128 * Q;
#pragma unroll
            for (int i = 0; i < 8; ++i) {
                float4 v = make_float4(acc[i][0], acc[i][1], acc[i][2], acc[i][3]);
                ((float4*)(oc + (size_t)(ty * 8 + i) * Q))[tx] = v;
            }
        }
        __syncthreads();
#pragma unroll
        for (int t = 0; t < 8; ++t) ((float4*)sT2)[tid + t * 512] = tB[t];
        if (ch + 2 < 4) {
            const float4* xc = (const float4*)(xb + (size_t)(ch + 2) * 128 * Q);
            const float4* gc = (const float4*)(gb + (size_t)(ch + 2) * 128 * Q);
#pragma unroll
            for (int t = 0; t < 8; ++t) {
                const int idx = tid + t * 512;
                const float4 xv = xc[idx];
                const float4 gv = gc[idx];
                tA[t] = make_float4(xv.x - lr * gv.x, xv.y - lr * gv.y,
                                    xv.z - lr * gv.z, xv.w - lr * gv.w);
            }
        }
        __syncthreads();
        {
            float acc[8][4];
#pragma unroll
            for (int i = 0; i < 8; ++i)
#pragma unroll
                for (int j = 0; j < 4; ++j) acc[i][j] = 0.0f;
            for (int k = 0; k < Q; ++k) {
                float a[8];
#pragma unroll
                for (int i = 0; i < 8; ++i) a[i] = sT2[(ty * 8 + i) * 128 + k];
                const float4 bv = ((const float4*)(sZf + k * Q))[tx];
                const float b[4] = {bv.x, bv.y, bv.z, bv.w};
#pragma unroll
                for (int i = 0; i < 8; ++i)
#pragma unroll
                    for (int j = 0; j < 4; ++j) acc[i][j] += a[i] * b[j];
            }
            float* oc = ob + (size_t)(ch + 1) * 128 * Q;
#pragma unroll
            for (int i = 0; i < 8; ++i) {
                float4 v = make_float4(acc[i][0], acc[i][1], acc[i][2], acc[i][3]);
                ((float4*)(oc + (size_t)(ty * 8 + i) * Q))[tx] = v;
            }
        }
    }
}

extern "C" void kernel_launch(void* const* d_in, const int* in_sizes, int n_in,
                              void* d_out, int out_size, void* d_ws, size_t ws_size,
                              hipStream_t stream) {
    const float* X  = (const float*)d_in[0];
    const float* G  = (const float*)d_in[1];
    const float* lr = (const float*)d_in[2];
    float* outp = (float*)d_out;
    float* gram = (float*)d_ws;                       // 16.8 MB
    float* Zg   = gram + (size_t)NBATCH * Q * Q;      // 16.8 MB

    gram_kernel<<<NBATCH, 512, 0, stream>>>(X, G, lr, gram);
    ns_kernel<<<NBATCH, 512, 0, stream>>>(gram, Zg);
    refine_kernel<<<NBATCH, 512, 0, stream>>>(gram, Zg);
    apply_kernel<<<NBATCH * 2, 512, 0, stream>>>(X, G, lr, Zg, outp);
}

// Round 7
// 443.543 us; speedup vs baseline: 2.0345x; 2.0345x over previous
//
#include <hip/hip_runtime.h>

#define NBATCH 256
#define P 1024
#define Q 128
#define NS_LOOP 10

typedef _Float16 half8 __attribute__((ext_vector_type(8)));
typedef float f32x4 __attribute__((ext_vector_type(4)));
struct Half4 { _Float16 x, y, z, w; };   // 8 bytes

// Swizzled fp16 storage for 128x128 symmetric matrices:
// element (r,c) -> Half4 slot r*32 + ((c>>2) ^ (r&15)), component c&3.
__device__ __forceinline__ half8 frag_ld(const Half4* S, int rowbase, int slotbase, int lane) {
    const int r = rowbase + (lane & 15);
    const int g = (lane >> 4);
    const int rx = r & 15;
    const Half4 h1 = S[r * 32 + ((slotbase + g) ^ rx)];
    const Half4 h2 = S[r * 32 + ((slotbase + g + 4) ^ rx)];
    half8 v;
    v[0] = h1.x; v[1] = h1.y; v[2] = h1.z; v[3] = h1.w;
    v[4] = h2.x; v[5] = h2.y; v[6] = h2.z; v[7] = h2.w;
    return v;
}

// C-fragment position, stored TRANSPOSED (ok: all iterates symmetric to O(eps)).
__device__ __forceinline__ int cpos(int RB, int CB, int lane) {
    const int r = CB + (lane & 15);
    const int s = (RB >> 2) + (lane >> 4);
    return r * 32 + (s ^ (r & 15));
}

__device__ __forceinline__ f32x4 cread(const Half4* S, int p) {
    const Half4 h = S[p];
    f32x4 v;
    v[0] = (float)h.x; v[1] = (float)h.y; v[2] = (float)h.z; v[3] = (float)h.w;
    return v;
}

__device__ __forceinline__ void cwrite(Half4* S, int p, f32x4 v) {
    Half4 h;
    h.x = (_Float16)v[0]; h.y = (_Float16)v[1]; h.z = (_Float16)v[2]; h.w = (_Float16)v[3];
    S[p] = h;
}

// ---------------------------------------------------------------------------
// Kernel 1: gram[n] = temp^T temp (fp32 VALU). ROUND-2 STRUCTURE, proven
// counter-clean: loads feed LDS immediately, NO register liveness across
// __syncthreads (r3-r6's cross-barrier prefetch caused 2.5GB phantom
// scratch traffic at VGPR cap 128).
// ---------------------------------------------------------------------------
__global__ __launch_bounds__(256) void gram_kernel(
    const float* __restrict__ X, const float* __restrict__ G,
    const float* __restrict__ lrp, float* __restrict__ gram)
{
    const int n = blockIdx.x;
    const float lr = *lrp;
    const float* xb = X + (size_t)n * P * Q;
    const float* gb = G + (size_t)n * P * Q;
    __shared__ float sT[32][Q];  // 16 KB
    const int tid = threadIdx.x;
    const int ty = tid >> 4, tx = tid & 15;

    float acc[8][8];
#pragma unroll
    for (int i = 0; i < 8; ++i)
#pragma unroll
        for (int j = 0; j < 8; ++j) acc[i][j] = 0.0f;

    for (int p0 = 0; p0 < P; p0 += 32) {
#pragma unroll
        for (int t = 0; t < 4; ++t) {
            const int idx = tid + t * 256;
            float4 xv = reinterpret_cast<const float4*>(xb + (size_t)p0 * Q)[idx];
            float4 gv = reinterpret_cast<const float4*>(gb + (size_t)p0 * Q)[idx];
            float4 tv;
            tv.x = xv.x - lr * gv.x; tv.y = xv.y - lr * gv.y;
            tv.z = xv.z - lr * gv.z; tv.w = xv.w - lr * gv.w;
            reinterpret_cast<float4*>(&sT[0][0])[idx] = tv;
        }
        __syncthreads();
        for (int p = 0; p < 32; ++p) {
            float4 a0 = *reinterpret_cast<const float4*>(&sT[p][ty * 8]);
            float4 a1 = *reinterpret_cast<const float4*>(&sT[p][ty * 8 + 4]);
            float4 b0 = *reinterpret_cast<const float4*>(&sT[p][tx * 8]);
            float4 b1 = *reinterpret_cast<const float4*>(&sT[p][tx * 8 + 4]);
            float a[8] = {a0.x, a0.y, a0.z, a0.w, a1.x, a1.y, a1.z, a1.w};
            float b[8] = {b0.x, b0.y, b0.z, b0.w, b1.x, b1.y, b1.z, b1.w};
#pragma unroll
            for (int i = 0; i < 8; ++i)
#pragma unroll
                for (int j = 0; j < 8; ++j) acc[i][j] += a[i] * b[j];
        }
        __syncthreads();
    }
    float* gm = gram + (size_t)n * Q * Q;
#pragma unroll
    for (int i = 0; i < 8; ++i) {
#pragma unroll
        for (int j = 0; j < 2; ++j) {
            float4 v = make_float4(acc[i][4 * j + 0], acc[i][4 * j + 1],
                                   acc[i][4 * j + 2], acc[i][4 * j + 3]);
            reinterpret_cast<float4*>(&gm[(size_t)(ty * 8 + i) * Q + tx * 8])[j] = v;
        }
    }
}

// ---------------------------------------------------------------------------
// Kernel 2: Newton-Schulz (fp16 MFMA), register-lean (round-6, counter-clean).
// 8 waves x 16-row strips; W ping-pongs between two LDS buffers.
// ---------------------------------------------------------------------------
__global__ __launch_bounds__(512) void ns_kernel(
    const float* __restrict__ gram, float* __restrict__ Zg)
{
    __shared__ __align__(16) unsigned char pool[98304];
    Half4* bufA = (Half4*)pool;
    Half4* bufB = (Half4*)(pool + 32768);
    Half4* sZh  = (Half4*)(pool + 65536);
    __shared__ float sRed[8];

    const int n = blockIdx.x;
    const int tid = threadIdx.x;
    const float* gm = gram + (size_t)n * Q * Q;

    float4 gv[8];
    float ss = 0.0f;
#pragma unroll
    for (int t = 0; t < 8; ++t) {
        gv[t] = ((const float4*)gm)[tid + t * 512];
        ss += gv[t].x * gv[t].x + gv[t].y * gv[t].y
            + gv[t].z * gv[t].z + gv[t].w * gv[t].w;
    }
#pragma unroll
    for (int off = 32; off > 0; off >>= 1) ss += __shfl_down(ss, off, 64);
    if ((tid & 63) == 0) sRed[tid >> 6] = ss;
    __syncthreads();
    float csum = 0.0f;
#pragma unroll
    for (int w = 0; w < 8; ++w) csum += sRed[w];
    const float c = sqrtf(csum);
    const float rc = 1.0f / c;
    const float rs = 1.0f / sqrtf(c);

#pragma unroll
    for (int t = 0; t < 8; ++t) {
        const int idx = tid + t * 512;
        const int row = idx >> 5, c4 = idx & 31;
        const int slot = row * 32 + (c4 ^ (row & 15));
        float wv[4], zv[4];
        wv[0] = gv[t].x * rc; wv[1] = gv[t].y * rc;
        wv[2] = gv[t].z * rc; wv[3] = gv[t].w * rc;
#pragma unroll
        for (int j = 0; j < 4; ++j)
            zv[j] = -0.5f * wv[j] + (((row >> 2) == c4 && (row & 3) == j) ? 1.5f : 0.0f);
        Half4 wh, zh;
        wh.x = (_Float16)wv[0]; wh.y = (_Float16)wv[1]; wh.z = (_Float16)wv[2]; wh.w = (_Float16)wv[3];
        zh.x = (_Float16)zv[0]; zh.y = (_Float16)zv[1]; zh.z = (_Float16)zv[2]; zh.w = (_Float16)zv[3];
        bufA[slot] = wh;
        sZh[slot] = zh;
    }
    __syncthreads();

    const int lane = tid & 63;
    const int wid = tid >> 6;
    const int RB = wid * 16;
    const f32x4 zero4 = {0.0f, 0.0f, 0.0f, 0.0f};
    Half4* cur = bufA;
    Half4* scr = bufB;

    for (int it = 0; it < NS_LOOP; ++it) {
        // M = 1.5W - 0.5 W*W -> scr
        f32x4 a1[8];
#pragma unroll
        for (int fj = 0; fj < 8; ++fj) a1[fj] = zero4;
#pragma unroll
        for (int kb = 0; kb < 4; ++kb) {
            const half8 af = frag_ld(cur, RB, kb * 8, lane);
#pragma unroll
            for (int fj = 0; fj < 8; ++fj) {
                const half8 bf = frag_ld(cur, fj * 16, kb * 8, lane);
                a1[fj] = __builtin_amdgcn_mfma_f32_16x16x32_f16(af, bf, a1[fj], 0, 0, 0);
            }
        }
#pragma unroll
        for (int fj = 0; fj < 8; ++fj) {
            const int p = cpos(RB, fj * 16, lane);
            cwrite(scr, p, 1.5f * cread(cur, p) - 0.5f * a1[fj]);
        }
        __syncthreads();

        // Wnew = 1.5M - 0.5 M*W
        f32x4 a2[8];
#pragma unroll
        for (int fj = 0; fj < 8; ++fj) a2[fj] = zero4;
#pragma unroll
        for (int kb = 0; kb < 4; ++kb) {
            const half8 af = frag_ld(scr, RB, kb * 8, lane);
#pragma unroll
            for (int fj = 0; fj < 8; ++fj) {
                const half8 bf = frag_ld(cur, fj * 16, kb * 8, lane);
                a2[fj] = __builtin_amdgcn_mfma_f32_16x16x32_f16(af, bf, a2[fj], 0, 0, 0);
            }
        }
        f32x4 wn[8];
#pragma unroll
        for (int fj = 0; fj < 8; ++fj) {
            const int p = cpos(RB, fj * 16, lane);
            wn[fj] = 1.5f * cread(scr, p) - 0.5f * a2[fj];
        }
        __syncthreads();
#pragma unroll
        for (int fj = 0; fj < 8; ++fj)
            cwrite(scr, cpos(RB, fj * 16, lane), wn[fj]);
        __syncthreads();

        // Znew = 1.5Z - 0.5 Wnew*Z
        f32x4 a3[8];
#pragma unroll
        for (int fj = 0; fj < 8; ++fj) a3[fj] = zero4;
#pragma unroll
        for (int kb = 0; kb < 4; ++kb) {
            const half8 af = frag_ld(scr, RB, kb * 8, lane);
#pragma unroll
            for (int fj = 0; fj < 8; ++fj) {
                const half8 bf = frag_ld(sZh, fj * 16, kb * 8, lane);
                a3[fj] = __builtin_amdgcn_mfma_f32_16x16x32_f16(af, bf, a3[fj], 0, 0, 0);
            }
        }
        f32x4 zn[8];
#pragma unroll
        for (int fj = 0; fj < 8; ++fj) {
            const int p = cpos(RB, fj * 16, lane);
            zn[fj] = 1.5f * cread(sZh, p) - 0.5f * a3[fj];
        }
        __syncthreads();
#pragma unroll
        for (int fj = 0; fj < 8; ++fj)
            cwrite(sZh, cpos(RB, fj * 16, lane), zn[fj]);
        __syncthreads();

        Half4* tmp = cur; cur = scr; scr = tmp;
    }

    float* zo = Zg + (size_t)n * Q * Q;
#pragma unroll
    for (int t = 0; t < 8; ++t) {
        const int idx = tid + t * 512;
        const int row = idx >> 5, c4 = idx & 31;
        const Half4 h = sZh[row * 32 + (c4 ^ (row & 15))];
        float4 o;
        o.x = (float)h.x * rs; o.y = (float)h.y * rs;
        o.z = (float)h.z * rs; o.w = (float)h.w * rs;
        ((float4*)(zo + row * Q))[c4] = o;
    }
}

// ---------------------------------------------------------------------------
// Kernel 3: one fp32 NS refinement step (round-6, counter-clean).
// ---------------------------------------------------------------------------
__global__ __launch_bounds__(512) void refine_kernel(
    const float* __restrict__ gram, float* __restrict__ Zg)
{
    __shared__ float sY[Q * Q];
    __shared__ float sU[Q * Q];
    __shared__ float sR[32 * Q];
    const int n = blockIdx.x;
    const int tid = threadIdx.x;
    const float* gm = gram + (size_t)n * Q * Q;
    float* zg = Zg + (size_t)n * Q * Q;
    const int ty = tid >> 5, tx = tid & 31;

#pragma unroll
    for (int t = 0; t < 8; ++t) {
        const int idx = tid + t * 512;
        ((float4*)sY)[idx] = ((const float4*)zg)[idx];
    }
    __syncthreads();

    {
        float acc[8][4];
#pragma unroll
        for (int i = 0; i < 8; ++i)
#pragma unroll
            for (int j = 0; j < 4; ++j) acc[i][j] = 0.0f;
        for (int k = 0; k < Q; ++k) {
            float a[8];
#pragma unroll
            for (int i = 0; i < 8; ++i) a[i] = sY[(ty * 8 + i) * Q + k];
            const float4 bv = ((const float4*)(sY + k * Q))[tx];
            const float b[4] = {bv.x, bv.y, bv.z, bv.w};
#pragma unroll
            for (int i = 0; i < 8; ++i)
#pragma unroll
                for (int j = 0; j < 4; ++j) acc[i][j] += a[i] * b[j];
        }
#pragma unroll
        for (int i = 0; i < 8; ++i) {
            float4 v = make_float4(acc[i][0], acc[i][1], acc[i][2], acc[i][3]);
            ((float4*)(sU + (ty * 8 + i) * Q))[tx] = v;
        }
    }
    __syncthreads();

    for (int ch = 0; ch < 4; ++ch) {
        const int r0 = ch * 32 + ty * 2;
        float acc[2][4];
#pragma unroll
        for (int i = 0; i < 2; ++i)
#pragma unroll
            for (int j = 0; j < 4; ++j) acc[i][j] = 0.0f;
        for (int k = 0; k < Q; ++k) {
            const float a0 = sY[(r0 + 0) * Q + k];
            const float a1 = sY[(r0 + 1) * Q + k];
            const float4 bv = ((const float4*)(gm + (size_t)k * Q))[tx];
            acc[0][0] += a0 * bv.x; acc[0][1] += a0 * bv.y;
            acc[0][2] += a0 * bv.z; acc[0][3] += a0 * bv.w;
            acc[1][0] += a1 * bv.x; acc[1][1] += a1 * bv.y;
            acc[1][2] += a1 * bv.z; acc[1][3] += a1 * bv.w;
        }
        __syncthreads();
#pragma unroll
        for (int i = 0; i < 2; ++i) {
            float4 v = make_float4(acc[i][0], acc[i][1], acc[i][2], acc[i][3]);
            ((float4*)(sR + (ty * 2 + i) * Q))[tx] = v;
        }
        __syncthreads();

        float acc2[2][4];
#pragma unroll
        for (int i = 0; i < 2; ++i)
#pragma unroll
            for (int j = 0; j < 4; ++j) acc2[i][j] = 0.0f;
        for (int k = 0; k < Q; ++k) {
            const float a0 = sR[(ty * 2 + 0) * Q + k];
            const float a1 = sR[(ty * 2 + 1) * Q + k];
            const float4 bv = ((const float4*)(sU + k * Q))[tx];
            acc2[0][0] += a0 * bv.x; acc2[0][1] += a0 * bv.y;
            acc2[0][2] += a0 * bv.z; acc2[0][3] += a0 * bv.w;
            acc2[1][0] += a1 * bv.x; acc2[1][1] += a1 * bv.y;
            acc2[1][2] += a1 * bv.z; acc2[1][3] += a1 * bv.w;
        }
#pragma unroll
        for (int i = 0; i < 2; ++i) {
            const float4 yv = ((const float4*)(sY + (r0 + i) * Q))[tx];
            float4 o;
            o.x = 1.5f * yv.x - 0.5f * acc2[i][0];
            o.y = 1.5f * yv.y - 0.5f * acc2[i][1];
            o.z = 1.5f * yv.z - 0.5f * acc2[i][2];
            o.w = 1.5f * yv.w - 0.5f * acc2[i][3];
            ((float4*)(zg + (size_t)(r0 + i) * Q))[tx] = o;
        }
    }
}

// ---------------------------------------------------------------------------
// Kernel 4: out[n] = temp[n] @ Zg[n]. ROUND-2 STRUCTURE (proven clean):
// 8 blocks/batch, 256 threads, immediate staging, no cross-barrier regs.
// ---------------------------------------------------------------------------
__global__ __launch_bounds__(256) void apply_kernel(
    const float* __restrict__ X, const float* __restrict__ G,
    const float* __restrict__ lrp, const float* __restrict__ Zg,
    float* __restrict__ out)
{
    const int n = blockIdx.x >> 3;
    const int p0 = (blockIdx.x & 7) * 128;
    const float lr = *lrp;
    const float* xb = X + (size_t)n * P * Q + (size_t)p0 * Q;
    const float* gb = G + (size_t)n * P * Q + (size_t)p0 * Q;
    float* ob = out + (size_t)n * P * Q + (size_t)p0 * Q;
    const float* zb = Zg + (size_t)n * Q * Q;

    __shared__ float sT[128][Q + 1];
    __shared__ float sZ[Q][Q];
    const int tid = threadIdx.x;
    const int ty = tid >> 4, tx = tid & 15;

#pragma unroll
    for (int t = 0; t < 16; ++t) {
        const int idx = tid + t * 256;
        reinterpret_cast<float4*>(&sZ[0][0])[idx] =
            reinterpret_cast<const float4*>(zb)[idx];
    }
#pragma unroll
    for (int t = 0; t < 16; ++t) {
        const int idx = tid + t * 256;
        const int p = idx >> 5, q4 = idx & 31;
        float4 xv = reinterpret_cast<const float4*>(xb + (size_t)p * Q)[q4];
        float4 gv = reinterpret_cast<const float4*>(gb + (size_t)p * Q)[q4];
        sT[p][q4 * 4 + 0] = xv.x - lr * gv.x;
        sT[p][q4 * 4 + 1] = xv.y - lr * gv.y;
        sT[p][q4 * 4 + 2] = xv.z - lr * gv.z;
        sT[p][q4 * 4 + 3] = xv.w - lr * gv.w;
    }
    __syncthreads();

    float acc[8][8];
#pragma unroll
    for (int i = 0; i < 8; ++i)
#pragma unroll
        for (int j = 0; j < 8; ++j) acc[i][j] = 0.0f;

    for (int q = 0; q < Q; ++q) {
        float a[8];
#pragma unroll
        for (int i = 0; i < 8; ++i) a[i] = sT[ty * 8 + i][q];
        float4 b0 = *reinterpret_cast<const float4*>(&sZ[q][tx * 8]);
        float4 b1 = *reinterpret_cast<const float4*>(&sZ[q][tx * 8 + 4]);
        float b[8] = {b0.x, b0.y, b0.z, b0.w, b1.x, b1.y, b1.z, b1.w};
#pragma unroll
        for (int i = 0; i < 8; ++i)
#pragma unroll
            for (int j = 0; j < 8; ++j) acc[i][j] += a[i] * b[j];
    }

#pragma unroll
    for (int i = 0; i < 8; ++i) {
#pragma unroll
        for (int j = 0; j < 2; ++j) {
            float4 v = make_float4(acc[i][4 * j + 0], acc[i][4 * j + 1],
                                   acc[i][4 * j + 2], acc[i][4 * j + 3]);
            reinterpret_cast<float4*>(&ob[(size_t)(ty * 8 + i) * Q + tx * 8])[j] = v;
        }
    }
}

extern "C" void kernel_launch(void* const* d_in, const int* in_sizes, int n_in,
                              void* d_out, int out_size, void* d_ws, size_t ws_size,
                              hipStream_t stream) {
    const float* X  = (const float*)d_in[0];
    const float* G  = (const float*)d_in[1];
    const float* lr = (const float*)d_in[2];
    float* outp = (float*)d_out;
    float* gram = (float*)d_ws;                       // 16.8 MB
    float* Zg   = gram + (size_t)NBATCH * Q * Q;      // 16.8 MB

    gram_kernel<<<NBATCH, 256, 0, stream>>>(X, G, lr, gram);
    ns_kernel<<<NBATCH, 512, 0, stream>>>(gram, Zg);
    refine_kernel<<<NBATCH, 512, 0, stream>>>(gram, Zg);
    apply_kernel<<<NBATCH * 8, 256, 0, stream>>>(X, G, lr, Zg, outp);
}

// Round 8
// 344.876 us; speedup vs baseline: 2.6165x; 1.2861x over previous
//
#include <hip/hip_runtime.h>

#define NBATCH 256
#define P 1024
#define Q 128
#define NS_LOOP 10

typedef _Float16 half8 __attribute__((ext_vector_type(8)));
typedef float f32x4 __attribute__((ext_vector_type(4)));
struct Half4 { _Float16 x, y, z, w; };   // 8 bytes

// Swizzled fp16 storage for 128x128 matrices:
// element (r,c) -> Half4 slot r*32 + ((c>>2) ^ (r&15)), component c&3.
__device__ __forceinline__ half8 frag_ld(const Half4* S, int rowbase, int slotbase, int lane) {
    const int r = rowbase + (lane & 15);
    const int g = (lane >> 4);
    const int rx = r & 15;
    const Half4 h1 = S[r * 32 + ((slotbase + g) ^ rx)];
    const Half4 h2 = S[r * 32 + ((slotbase + g + 4) ^ rx)];
    half8 v;
    v[0] = h1.x; v[1] = h1.y; v[2] = h1.z; v[3] = h1.w;
    v[4] = h2.x; v[5] = h2.y; v[6] = h2.z; v[7] = h2.w;
    return v;
}

// C-fragment position, stored TRANSPOSED (ok: all iterates symmetric to O(eps)).
__device__ __forceinline__ int cpos(int RB, int CB, int lane) {
    const int r = CB + (lane & 15);
    const int s = (RB >> 2) + (lane >> 4);
    return r * 32 + (s ^ (r & 15));
}

__device__ __forceinline__ f32x4 cread(const Half4* S, int p) {
    const Half4 h = S[p];
    f32x4 v;
    v[0] = (float)h.x; v[1] = (float)h.y; v[2] = (float)h.z; v[3] = (float)h.w;
    return v;
}

__device__ __forceinline__ void cwrite(Half4* S, int p, f32x4 v) {
    Half4 h;
    h.x = (_Float16)v[0]; h.y = (_Float16)v[1]; h.z = (_Float16)v[2]; h.w = (_Float16)v[3];
    S[p] = h;
}

// ---------------------------------------------------------------------------
// Kernel 1: gram[n] = temp^T temp (fp32 VALU). Round-2 structure, counter-clean.
// ---------------------------------------------------------------------------
__global__ __launch_bounds__(256) void gram_kernel(
    const float* __restrict__ X, const float* __restrict__ G,
    const float* __restrict__ lrp, float* __restrict__ gram)
{
    const int n = blockIdx.x;
    const float lr = *lrp;
    const float* xb = X + (size_t)n * P * Q;
    const float* gb = G + (size_t)n * P * Q;
    __shared__ float sT[32][Q];  // 16 KB
    const int tid = threadIdx.x;
    const int ty = tid >> 4, tx = tid & 15;

    float acc[8][8];
#pragma unroll
    for (int i = 0; i < 8; ++i)
#pragma unroll
        for (int j = 0; j < 8; ++j) acc[i][j] = 0.0f;

    for (int p0 = 0; p0 < P; p0 += 32) {
#pragma unroll
        for (int t = 0; t < 4; ++t) {
            const int idx = tid + t * 256;
            float4 xv = reinterpret_cast<const float4*>(xb + (size_t)p0 * Q)[idx];
            float4 gv = reinterpret_cast<const float4*>(gb + (size_t)p0 * Q)[idx];
            float4 tv;
            tv.x = xv.x - lr * gv.x; tv.y = xv.y - lr * gv.y;
            tv.z = xv.z - lr * gv.z; tv.w = xv.w - lr * gv.w;
            reinterpret_cast<float4*>(&sT[0][0])[idx] = tv;
        }
        __syncthreads();
        for (int p = 0; p < 32; ++p) {
            float4 a0 = *reinterpret_cast<const float4*>(&sT[p][ty * 8]);
            float4 a1 = *reinterpret_cast<const float4*>(&sT[p][ty * 8 + 4]);
            float4 b0 = *reinterpret_cast<const float4*>(&sT[p][tx * 8]);
            float4 b1 = *reinterpret_cast<const float4*>(&sT[p][tx * 8 + 4]);
            float a[8] = {a0.x, a0.y, a0.z, a0.w, a1.x, a1.y, a1.z, a1.w};
            float b[8] = {b0.x, b0.y, b0.z, b0.w, b1.x, b1.y, b1.z, b1.w};
#pragma unroll
            for (int i = 0; i < 8; ++i)
#pragma unroll
                for (int j = 0; j < 8; ++j) acc[i][j] += a[i] * b[j];
        }
        __syncthreads();
    }
    float* gm = gram + (size_t)n * Q * Q;
#pragma unroll
    for (int i = 0; i < 8; ++i) {
#pragma unroll
        for (int j = 0; j < 2; ++j) {
            float4 v = make_float4(acc[i][4 * j + 0], acc[i][4 * j + 1],
                                   acc[i][4 * j + 2], acc[i][4 * j + 3]);
            reinterpret_cast<float4*>(&gm[(size_t)(ty * 8 + i) * Q + tx * 8])[j] = v;
        }
    }
}

// ---------------------------------------------------------------------------
// Kernel 2: Newton-Schulz (fp16 MFMA), register-lean (counter-clean).
// ---------------------------------------------------------------------------
__global__ __launch_bounds__(512) void ns_kernel(
    const float* __restrict__ gram, float* __restrict__ Zg)
{
    __shared__ __align__(16) unsigned char pool[98304];
    Half4* bufA = (Half4*)pool;
    Half4* bufB = (Half4*)(pool + 32768);
    Half4* sZh  = (Half4*)(pool + 65536);
    __shared__ float sRed[8];

    const int n = blockIdx.x;
    const int tid = threadIdx.x;
    const float* gm = gram + (size_t)n * Q * Q;

    float4 gv[8];
    float ss = 0.0f;
#pragma unroll
    for (int t = 0; t < 8; ++t) {
        gv[t] = ((const float4*)gm)[tid + t * 512];
        ss += gv[t].x * gv[t].x + gv[t].y * gv[t].y
            + gv[t].z * gv[t].z + gv[t].w * gv[t].w;
    }
#pragma unroll
    for (int off = 32; off > 0; off >>= 1) ss += __shfl_down(ss, off, 64);
    if ((tid & 63) == 0) sRed[tid >> 6] = ss;
    __syncthreads();
    float csum = 0.0f;
#pragma unroll
    for (int w = 0; w < 8; ++w) csum += sRed[w];
    const float c = sqrtf(csum);
    const float rc = 1.0f / c;
    const float rs = 1.0f / sqrtf(c);

#pragma unroll
    for (int t = 0; t < 8; ++t) {
        const int idx = tid + t * 512;
        const int row = idx >> 5, c4 = idx & 31;
        const int slot = row * 32 + (c4 ^ (row & 15));
        float wv[4], zv[4];
        wv[0] = gv[t].x * rc; wv[1] = gv[t].y * rc;
        wv[2] = gv[t].z * rc; wv[3] = gv[t].w * rc;
#pragma unroll
        for (int j = 0; j < 4; ++j)
            zv[j] = -0.5f * wv[j] + (((row >> 2) == c4 && (row & 3) == j) ? 1.5f : 0.0f);
        Half4 wh, zh;
        wh.x = (_Float16)wv[0]; wh.y = (_Float16)wv[1]; wh.z = (_Float16)wv[2]; wh.w = (_Float16)wv[3];
        zh.x = (_Float16)zv[0]; zh.y = (_Float16)zv[1]; zh.z = (_Float16)zv[2]; zh.w = (_Float16)zv[3];
        bufA[slot] = wh;
        sZh[slot] = zh;
    }
    __syncthreads();

    const int lane = tid & 63;
    const int wid = tid >> 6;
    const int RB = wid * 16;
    const f32x4 zero4 = {0.0f, 0.0f, 0.0f, 0.0f};
    Half4* cur = bufA;
    Half4* scr = bufB;

    for (int it = 0; it < NS_LOOP; ++it) {
        f32x4 a1[8];
#pragma unroll
        for (int fj = 0; fj < 8; ++fj) a1[fj] = zero4;
#pragma unroll
        for (int kb = 0; kb < 4; ++kb) {
            const half8 af = frag_ld(cur, RB, kb * 8, lane);
#pragma unroll
            for (int fj = 0; fj < 8; ++fj) {
                const half8 bf = frag_ld(cur, fj * 16, kb * 8, lane);
                a1[fj] = __builtin_amdgcn_mfma_f32_16x16x32_f16(af, bf, a1[fj], 0, 0, 0);
            }
        }
#pragma unroll
        for (int fj = 0; fj < 8; ++fj) {
            const int p = cpos(RB, fj * 16, lane);
            cwrite(scr, p, 1.5f * cread(cur, p) - 0.5f * a1[fj]);
        }
        __syncthreads();

        f32x4 a2[8];
#pragma unroll
        for (int fj = 0; fj < 8; ++fj) a2[fj] = zero4;
#pragma unroll
        for (int kb = 0; kb < 4; ++kb) {
            const half8 af = frag_ld(scr, RB, kb * 8, lane);
#pragma unroll
            for (int fj = 0; fj < 8; ++fj) {
                const half8 bf = frag_ld(cur, fj * 16, kb * 8, lane);
                a2[fj] = __builtin_amdgcn_mfma_f32_16x16x32_f16(af, bf, a2[fj], 0, 0, 0);
            }
        }
        f32x4 wn[8];
#pragma unroll
        for (int fj = 0; fj < 8; ++fj) {
            const int p = cpos(RB, fj * 16, lane);
            wn[fj] = 1.5f * cread(scr, p) - 0.5f * a2[fj];
        }
        __syncthreads();
#pragma unroll
        for (int fj = 0; fj < 8; ++fj)
            cwrite(scr, cpos(RB, fj * 16, lane), wn[fj]);
        __syncthreads();

        f32x4 a3[8];
#pragma unroll
        for (int fj = 0; fj < 8; ++fj) a3[fj] = zero4;
#pragma unroll
        for (int kb = 0; kb < 4; ++kb) {
            const half8 af = frag_ld(scr, RB, kb * 8, lane);
#pragma unroll
            for (int fj = 0; fj < 8; ++fj) {
                const half8 bf = frag_ld(sZh, fj * 16, kb * 8, lane);
                a3[fj] = __builtin_amdgcn_mfma_f32_16x16x32_f16(af, bf, a3[fj], 0, 0, 0);
            }
        }
        f32x4 zn[8];
#pragma unroll
        for (int fj = 0; fj < 8; ++fj) {
            const int p = cpos(RB, fj * 16, lane);
            zn[fj] = 1.5f * cread(sZh, p) - 0.5f * a3[fj];
        }
        __syncthreads();
#pragma unroll
        for (int fj = 0; fj < 8; ++fj)
            cwrite(sZh, cpos(RB, fj * 16, lane), zn[fj]);
        __syncthreads();

        Half4* tmp = cur; cur = scr; scr = tmp;
    }

    float* zo = Zg + (size_t)n * Q * Q;
#pragma unroll
    for (int t = 0; t < 8; ++t) {
        const int idx = tid + t * 512;
        const int row = idx >> 5, c4 = idx & 31;
        const Half4 h = sZh[row * 32 + (c4 ^ (row & 15))];
        float4 o;
        o.x = (float)h.x * rs; o.y = (float)h.y * rs;
        o.z = (float)h.z * rs; o.w = (float)h.w * rs;
        ((float4*)(zo + row * Q))[c4] = o;
    }
}

// ---------------------------------------------------------------------------
// Kernel 3: one fp32 NS refinement step (counter-clean).
// ---------------------------------------------------------------------------
__global__ __launch_bounds__(512) void refine_kernel(
    const float* __restrict__ gram, float* __restrict__ Zg)
{
    __shared__ float sY[Q * Q];
    __shared__ float sU[Q * Q];
    __shared__ float sR[32 * Q];
    const int n = blockIdx.x;
    const int tid = threadIdx.x;
    const float* gm = gram + (size_t)n * Q * Q;
    float* zg = Zg + (size_t)n * Q * Q;
    const int ty = tid >> 5, tx = tid & 31;

#pragma unroll
    for (int t = 0; t < 8; ++t) {
        const int idx = tid + t * 512;
        ((float4*)sY)[idx] = ((const float4*)zg)[idx];
    }
    __syncthreads();

    {
        float acc[8][4];
#pragma unroll
        for (int i = 0; i < 8; ++i)
#pragma unroll
            for (int j = 0; j < 4; ++j) acc[i][j] = 0.0f;
        for (int k = 0; k < Q; ++k) {
            float a[8];
#pragma unroll
            for (int i = 0; i < 8; ++i) a[i] = sY[(ty * 8 + i) * Q + k];
            const float4 bv = ((const float4*)(sY + k * Q))[tx];
            const float b[4] = {bv.x, bv.y, bv.z, bv.w};
#pragma unroll
            for (int i = 0; i < 8; ++i)
#pragma unroll
                for (int j = 0; j < 4; ++j) acc[i][j] += a[i] * b[j];
        }
#pragma unroll
        for (int i = 0; i < 8; ++i) {
            float4 v = make_float4(acc[i][0], acc[i][1], acc[i][2], acc[i][3]);
            ((float4*)(sU + (ty * 8 + i) * Q))[tx] = v;
        }
    }
    __syncthreads();

    for (int ch = 0; ch < 4; ++ch) {
        const int r0 = ch * 32 + ty * 2;
        float acc[2][4];
#pragma unroll
        for (int i = 0; i < 2; ++i)
#pragma unroll
            for (int j = 0; j < 4; ++j) acc[i][j] = 0.0f;
        for (int k = 0; k < Q; ++k) {
            const float a0 = sY[(r0 + 0) * Q + k];
            const float a1 = sY[(r0 + 1) * Q + k];
            const float4 bv = ((const float4*)(gm + (size_t)k * Q))[tx];
            acc[0][0] += a0 * bv.x; acc[0][1] += a0 * bv.y;
            acc[0][2] += a0 * bv.z; acc[0][3] += a0 * bv.w;
            acc[1][0] += a1 * bv.x; acc[1][1] += a1 * bv.y;
            acc[1][2] += a1 * bv.z; acc[1][3] += a1 * bv.w;
        }
        __syncthreads();
#pragma unroll
        for (int i = 0; i < 2; ++i) {
            float4 v = make_float4(acc[i][0], acc[i][1], acc[i][2], acc[i][3]);
            ((float4*)(sR + (ty * 2 + i) * Q))[tx] = v;
        }
        __syncthreads();

        float acc2[2][4];
#pragma unroll
        for (int i = 0; i < 2; ++i)
#pragma unroll
            for (int j = 0; j < 4; ++j) acc2[i][j] = 0.0f;
        for (int k = 0; k < Q; ++k) {
            const float a0 = sR[(ty * 2 + 0) * Q + k];
            const float a1 = sR[(ty * 2 + 1) * Q + k];
            const float4 bv = ((const float4*)(sU + k * Q))[tx];
            acc2[0][0] += a0 * bv.x; acc2[0][1] += a0 * bv.y;
            acc2[0][2] += a0 * bv.z; acc2[0][3] += a0 * bv.w;
            acc2[1][0] += a1 * bv.x; acc2[1][1] += a1 * bv.y;
            acc2[1][2] += a1 * bv.z; acc2[1][3] += a1 * bv.w;
        }
#pragma unroll
        for (int i = 0; i < 2; ++i) {
            const float4 yv = ((const float4*)(sY + (r0 + i) * Q))[tx];
            float4 o;
            o.x = 1.5f * yv.x - 0.5f * acc2[i][0];
            o.y = 1.5f * yv.y - 0.5f * acc2[i][1];
            o.z = 1.5f * yv.z - 0.5f * acc2[i][2];
            o.w = 1.5f * yv.w - 0.5f * acc2[i][3];
            ((float4*)(zg + (size_t)(r0 + i) * Q))[tx] = o;
        }
    }
}

// ---------------------------------------------------------------------------
// Kernel 4: out[n] = temp[n] @ Zg[n], fp16 MFMA.
// 8 blocks/batch (128 rows), 512 threads = 8 waves x 16-row strips.
// LDS: temp fp16 swizzled 32KB + Zg fp16 swizzled 32KB = 64KB -> 2 blocks/CU.
// A-frag = temp rows (m = lane&15); B-frag = Zg rows -> supplies Zg^T;
// D = temp * Zg^T = temp * Zg (Zg symmetric to ~5e-4).
// D store per m89-verified C layout: row = (lane>>4)*4+reg, col = lane&15.
// ---------------------------------------------------------------------------
__global__ __launch_bounds__(512) void apply_kernel(
    const float* __restrict__ X, const float* __restrict__ G,
    const float* __restrict__ lrp, const float* __restrict__ Zg,
    float* __restrict__ out)
{
    __shared__ __align__(16) unsigned char pool[65536];
    Half4* sTh = (Half4*)pool;              // temp tile, fp16 swizzled
    Half4* sZh = (Half4*)(pool + 32768);    // Zg, fp16 swizzled

    const int n = blockIdx.x >> 3;
    const int p0 = (blockIdx.x & 7) * 128;
    const int tid = threadIdx.x;
    const float lr = *lrp;
    const float* xb = X + (size_t)n * P * Q + (size_t)p0 * Q;
    const float* gb = G + (size_t)n * P * Q + (size_t)p0 * Q;
    const float* zb = Zg + (size_t)n * Q * Q;
    float* ob = out + (size_t)n * P * Q + (size_t)p0 * Q;

    // stage Zg -> fp16 swizzled (4096 float4, 8/thread)
#pragma unroll
    for (int t = 0; t < 8; ++t) {
        const int idx = tid + t * 512;
        const int row = idx >> 5, c4 = idx & 31;
        const float4 v = ((const float4*)zb)[idx];
        Half4 h;
        h.x = (_Float16)v.x; h.y = (_Float16)v.y;
        h.z = (_Float16)v.z; h.w = (_Float16)v.w;
        sZh[row * 32 + (c4 ^ (row & 15))] = h;
    }
    // stage temp -> fp16 swizzled
#pragma unroll
    for (int t = 0; t < 8; ++t) {
        const int idx = tid + t * 512;
        const int row = idx >> 5, c4 = idx & 31;
        const float4 xv = ((const float4*)xb)[idx];
        const float4 gv = ((const float4*)gb)[idx];
        Half4 h;
        h.x = (_Float16)(xv.x - lr * gv.x);
        h.y = (_Float16)(xv.y - lr * gv.y);
        h.z = (_Float16)(xv.z - lr * gv.z);
        h.w = (_Float16)(xv.w - lr * gv.w);
        sTh[row * 32 + (c4 ^ (row & 15))] = h;
    }
    __syncthreads();

    const int lane = tid & 63;
    const int wid = tid >> 6;
    const int RB = wid * 16;             // 16-row output strip
    const f32x4 zero4 = {0.0f, 0.0f, 0.0f, 0.0f};

    f32x4 a[8];
#pragma unroll
    for (int fj = 0; fj < 8; ++fj) a[fj] = zero4;
#pragma unroll
    for (int kb = 0; kb < 4; ++kb) {
        const half8 af = frag_ld(sTh, RB, kb * 8, lane);
#pragma unroll
        for (int fj = 0; fj < 8; ++fj) {
            const half8 bf = frag_ld(sZh, fj * 16, kb * 8, lane);
            a[fj] = __builtin_amdgcn_mfma_f32_16x16x32_f16(af, bf, a[fj], 0, 0, 0);
        }
    }

    // store: D[m][nn] -> out[RB + m][fj*16 + nn], m = (lane>>4)*4 + j, nn = lane&15
    const int m0 = (lane >> 4) * 4;
    const int nn = lane & 15;
#pragma unroll
    for (int fj = 0; fj < 8; ++fj) {
#pragma unroll
        for (int j = 0; j < 4; ++j) {
            ob[(size_t)(RB + m0 + j) * Q + fj * 16 + nn] = a[fj][j];
        }
    }
}

extern "C" void kernel_launch(void* const* d_in, const int* in_sizes, int n_in,
                              void* d_out, int out_size, void* d_ws, size_t ws_size,
                              hipStream_t stream) {
    const float* X  = (const float*)d_in[0];
    const float* G  = (const float*)d_in[1];
    const float* lr = (const float*)d_in[2];
    float* outp = (float*)d_out;
    float* gram = (float*)d_ws;                       // 16.8 MB
    float* Zg   = gram + (size_t)NBATCH * Q * Q;      // 16.8 MB

    gram_kernel<<<NBATCH, 256, 0, stream>>>(X, G, lr, gram);
    ns_kernel<<<NBATCH, 512, 0, stream>>>(gram, Zg);
    refine_kernel<<<NBATCH, 512, 0, stream>>>(gram, Zg);
    apply_kernel<<<NBATCH * 8, 512, 0, stream>>>(X, G, lr, Zg, outp);
}